// Round 14
// baseline (332.365 us; speedup 1.0000x reference)
//
#include <hip/hip_runtime.h>

#define EPS_ 1e-5f

typedef float f32x4 __attribute__((ext_vector_type(4)));
typedef short s16x8 __attribute__((ext_vector_type(8)));

static __device__ __forceinline__ short f2bf(float f) {
    unsigned u = __float_as_uint(f);
    unsigned r = (u + 0x7FFFu + ((u >> 16) & 1u)) >> 16;
    return (short)r;
}
static __device__ __forceinline__ float bf2f(short s) {
    return __uint_as_float(((unsigned)(unsigned short)s) << 16);
}

// async global->LDS, 16B per lane, wave-uniform LDS base
static __device__ __forceinline__ void gload16(const short* g, short* l) {
    __builtin_amdgcn_global_load_lds(
        (const __attribute__((address_space(1))) unsigned int*)g,
        (__attribute__((address_space(3))) unsigned int*)l, 16, 0, 0);
}

// ---------------------------------------------------------------------------
// Kernel 0: convert weight stacks to bf16 once.
// ---------------------------------------------------------------------------
__global__ __launch_bounds__(256) void prep_kernel(
    const float* __restrict__ Wq, const float* __restrict__ Wk,
    const float* __restrict__ Wv, const float* __restrict__ Wp,
    short* __restrict__ Wbf, short* __restrict__ Wpbf)
{
    int i = blockIdx.x * 256 + threadIdx.x;
    if (i < 6144) {
        float v = (i < 1024) ? Wq[i] : (i < 2048 ? Wk[i - 1024] : Wv[i - 2048]);
        Wbf[i] = f2bf(v);
    } else if (i < 6144 + 4096) {
        Wpbf[i - 6144] = f2bf(Wp[i - 6144]);
    }
}

// ---------------------------------------------------------------------------
// Kernel 1: QKV projection via MFMA + PReLU + LN(chan,freq), write bf16.
// ---------------------------------------------------------------------------
__global__ __launch_bounds__(256) void qkv_kernel(
    const float* __restrict__ x, const short* __restrict__ Wbf,
    const float* __restrict__ bq, const float* __restrict__ aq,
    const float* __restrict__ gq, const float* __restrict__ betq,
    const float* __restrict__ bk, const float* __restrict__ ak,
    const float* __restrict__ gk, const float* __restrict__ betk,
    const float* __restrict__ bv, const float* __restrict__ av,
    const float* __restrict__ gv, const float* __restrict__ betv,
    short* __restrict__ Qo, short* __restrict__ Ko, short* __restrict__ Vo)
{
    const int t = blockIdx.x;
    const int b = blockIdx.y;
    const int tid = threadIdx.x;
    const int wid = tid >> 6, lane = tid & 63;
    const int g = lane >> 4, c16 = lane & 15;
    const int f_ = tid & 63, cg = tid >> 6;

    __shared__ __align__(16) short wlds[96 * 64];
    __shared__ __align__(16) short xs[64 * 64];
    __shared__ float zs[96 * 64];
    __shared__ float stats[12][2];
    __shared__ float bias_l[96], alpha_l[96];

#pragma unroll
    for (int j = 0; j < 3; ++j) {
        int i8 = tid + 256 * j;
        int row = i8 >> 3, cb = i8 & 7;
        s16x8 v = *(const s16x8*)(Wbf + i8 * 8);
        *(s16x8*)&wlds[row * 64 + ((cb ^ (row & 7)) * 8)] = v;
    }
    if (tid < 96) {
        int row = tid; float bias, al;
        if (row < 16)      { bias = bq[row];      al = aq[row >> 2]; }
        else if (row < 32) { bias = bk[row - 16]; al = ak[(row - 16) >> 2]; }
        else               { bias = bv[row - 32]; al = av[(row - 32) >> 4]; }
        bias_l[row] = bias; alpha_l[row] = al;
    }
#pragma unroll
    for (int it = 0; it < 2; ++it) {
        int cb = cg + 4 * it, c0 = cb * 8;
        s16x8 v;
#pragma unroll
        for (int i = 0; i < 8; ++i)
            v[i] = f2bf(x[(((size_t)b * 64 + c0 + i) * 2048 + t) * 64 + f_]);
        *(s16x8*)&xs[f_ * 64 + ((cb ^ (f_ & 7)) * 8)] = v;
    }
    __syncthreads();

    const int f0 = wid * 16;
    s16x8 bfr[2];
#pragma unroll
    for (int kk = 0; kk < 2; ++kk)
        bfr[kk] = *(const s16x8*)&xs[(f0 + c16) * 64 + (((kk * 4 + g) ^ (c16 & 7)) * 8)];

    f32x4 acc[6];
#pragma unroll
    for (int rt = 0; rt < 6; ++rt) {
#pragma unroll
        for (int r = 0; r < 4; ++r) acc[rt][r] = 0.f;
#pragma unroll
        for (int kk = 0; kk < 2; ++kk) {
            s16x8 a = *(const s16x8*)&wlds[(rt * 16 + c16) * 64 + (((kk * 4 + g) ^ (c16 & 7)) * 8)];
            acc[rt] = __builtin_amdgcn_mfma_f32_16x16x32_bf16(a, bfr[kk], acc[rt], 0, 0, 0);
        }
    }

#pragma unroll
    for (int rt = 0; rt < 6; ++rt)
#pragma unroll
        for (int r = 0; r < 4; ++r) {
            int row = rt * 16 + g * 4 + r;
            float z = acc[rt][r] + bias_l[row];
            z = z >= 0.f ? z : alpha_l[row] * z;
            zs[row * 64 + f0 + c16] = z;
        }
    __syncthreads();

#pragma unroll
    for (int gi = 0; gi < 3; ++gi) {
        int grp = wid * 3 + gi;
        int base_row, n;
        if (grp < 4)      { base_row = grp * 4;             n = 256; }
        else if (grp < 8) { base_row = 16 + (grp - 4) * 4;  n = 256; }
        else              { base_row = 32 + (grp - 8) * 16; n = 1024; }
        int cnt = n >> 6;
        float s = 0.f, ss = 0.f;
        for (int i = 0; i < cnt; ++i) {
            float v = zs[(base_row + i) * 64 + lane];
            s += v; ss += v * v;
        }
#pragma unroll
        for (int msk = 32; msk >= 1; msk >>= 1) {
            s  += __shfl_xor(s, msk);
            ss += __shfl_xor(ss, msk);
        }
        if (lane == 0) {
            float mean = s / n;
            float var = ss / n - mean * mean;
            stats[grp][0] = mean;
            stats[grp][1] = rsqrtf(var + EPS_);
        }
    }
    __syncthreads();

#pragma unroll
    for (int j = 0; j < 24; ++j) {
        int row = cg + 4 * j;
        float zv = zs[row * 64 + f_];
        if (row < 16) {
            int grp = row >> 2;
            float val = (zv - stats[grp][0]) * stats[grp][1];
            val = val * gq[row * 64 + f_] + betq[row * 64 + f_];
            int h = row >> 2, o = row & 3;
            Qo[(((size_t)(h * 2 + b)) * 2048 + t) * 256 + o * 64 + f_] = f2bf(val);
        } else if (row < 32) {
            int rr = row - 16, grp = 4 + (rr >> 2);
            float val = (zv - stats[grp][0]) * stats[grp][1];
            val = val * gk[rr * 64 + f_] + betk[rr * 64 + f_];
            int h = rr >> 2, o = rr & 3;
            Ko[(((size_t)(h * 2 + b)) * 2048 + t) * 256 + o * 64 + f_] = f2bf(val);
        } else {
            int rr = row - 32, grp = 8 + (rr >> 4);
            float val = (zv - stats[grp][0]) * stats[grp][1];
            val = val * gv[rr * 64 + f_] + betv[rr * 64 + f_];
            int h = rr >> 4, ov = rr & 15;
            Vo[(((size_t)(h * 2 + b)) * 2048 + t) * 1024 + ov * 64 + f_] = f2bf(val);
        }
    }
}

// ---------------------------------------------------------------------------
// Kernel 2: V row-major [hb][t][d] -> V^T [hb][d][pi(t)] where pi relabels
// keys within each 32-aligned t-block so the in-register P from swapped
// QK^T feeds PV's A-operand with zero cross-lane movement.
// k' bits (b4 b3 b2 b1 b0) -> phys = b2*16 + b4*8 + b3*4 + b1b0.
// ---------------------------------------------------------------------------
__global__ __launch_bounds__(256) void vtrans_kernel(
    const short* __restrict__ Vrm, short* __restrict__ Vt)
{
    const int t0 = blockIdx.x * 64;
    const int d0 = blockIdx.y * 64;
    const int hb = blockIdx.z;
    const int tid = threadIdx.x;
    __shared__ __align__(16) short tile[64 * 72];

#pragma unroll
    for (int k = 0; k < 2; ++k) {
        int q = tid + 256 * k;
        int row = q >> 3, slot = q & 7;
        s16x8 v = *(const s16x8*)(Vrm + ((size_t)hb * 2048 + t0 + row) * 1024 + d0 + slot * 8);
        *(s16x8*)&tile[row * 72 + slot * 8] = v;
    }
    __syncthreads();
#pragma unroll
    for (int k = 0; k < 2; ++k) {
        int q = tid + 256 * k;
        int drow = q >> 3, tslot = q & 7;
        s16x8 v;
#pragma unroll
        for (int i = 0; i < 8; ++i) {
            int c = tslot * 8 + i;
            int cl = c & 31;
            int src = (c & 32) + ((cl >> 2) & 1) * 16 + ((cl >> 4) & 1) * 8
                    + ((cl >> 3) & 1) * 4 + (cl & 3);
            v[i] = tile[src * 72 + drow];
        }
        *(s16x8*)(Vt + ((size_t)hb * 1024 + d0 + drow) * 2048 + t0 + tslot * 8) = v;
    }
}

// ---------------------------------------------------------------------------
// Kernel 3: flash attention — KBLK=64 key-split, V direct global->reg.
// Grid (8 hb, 32 qt) = 256 blocks (1/CU), 512 thr (8 waves). QBLK=64,
// full d (QK^T computed exactly once chip-wide). 32 k-tiles of 64 keys.
// QK^T (swapped, wave = qs(4) x kp(2)): wave owns q-stripe qs (16 rows) x
//   key-half kp (32 keys): 16 K reads + 16 MFMA; softmax partial l
//   in-register (8 exp + 2 shfl); pa packed via pi -> 1 ds_write_b128.
//   K redundancy 4x (was 8x).
// PV: wave owns d-slice [wid*128,+128) for all 64 q; V fragments loaded
//   DIRECT from global (L2-hot: hb-affine grid keeps each head's 4MB V in
//   one XCD L2), issued at tile top - QK^T covers the latency. V is OFF
//   the LDS pipe entirely. 8 P reads + 16 V loads -> 64 MFMA.
// Pipeline: K DMA t+2 ahead, P double-buffered, ONE barrier per 64-key
//   tile (32 barriers total, was 64).
// LDS: K 2x32KB + P 2x8KB = 80KB. Regs ~115 VGPR + 128 AGPR.
// ---------------------------------------------------------------------------
__global__ __launch_bounds__(512, 2) void attn_kernel(
    const short* __restrict__ Qg, const short* __restrict__ Kg,
    const short* __restrict__ Vt, short* __restrict__ Ob)
{
    const int hb = blockIdx.x;
    const int qt = blockIdx.y;     // 0..31
    const int t0 = qt * 64;
    const int tid = threadIdx.x;
    const int lane = tid & 63;
    const int wid = tid >> 6;
    const int qs = wid >> 1;       // q-stripe (QK^T), 0..3
    const int kp = wid & 1;        // key-half (QK^T)
    const int g = lane >> 4, c16 = lane & 15;

    __shared__ __align__(16) short k_lds[2][64 * 256];   // 2x32 KB
    __shared__ __align__(16) short p_lds[2][4][2][512];  // 2x8 KB
    __shared__ float l_sh[2][64];

    const size_t kgbase = (size_t)hb * 2048 * 256;
    const size_t vgbase = (size_t)hb * 1024 * 2048;
    const int dsl = wid * 128;     // this wave's V d-slice (PV role)

    // Q B-fragments for q-stripe qs (16 rows x 256 d), persistent
    const size_t qrow = (size_t)hb * 2048 + t0 + qs * 16 + c16;
    s16x8 qf[8];
#pragma unroll
    for (int kf = 0; kf < 8; ++kf)
        qf[kf] = *(const s16x8*)(Qg + qrow * 256 + kf * 32 + g * 8);

    f32x4 oacc[32];                // [qs2 0..3][dt 0..7]
#pragma unroll
    for (int i = 0; i < 32; ++i)
#pragma unroll
        for (int r = 0; r < 4; ++r) oacc[i][r] = 0.f;

    float l_r = 0.f;               // partial softmax denom for q = c16 (kp half)

    // DMA-stage 64x256 K tile: linear LDS dest, inverse-swizzled source
#define STAGE_K(buf, kt) do {                                                  \
    _Pragma("unroll")                                                          \
    for (int j_ = 0; j_ < 4; ++j_) {                                           \
        int c_ = tid + 512 * j_;                                               \
        int row_ = c_ >> 5, sp_ = c_ & 31;                                     \
        int sl_ = sp_ ^ (row_ & 7);                                            \
        gload16(Kg + kgbase + (size_t)((kt) * 64 + row_) * 256 + sl_ * 8,      \
                &k_lds[buf][c_ * 8]);                                          \
    }                                                                          \
} while (0)

    // QK^T for tile nt (swapped, key-half kp): 16 q x 32 keys, 16 MFMA.
    // Lane ends with P[key][q=c16]; packed via pi into pa; 1 b128 write.
#define QKT_PHASE(nt) do {                                                     \
    f32x4 sf0, sf1;                                                            \
    _Pragma("unroll")                                                          \
    for (int r = 0; r < 4; ++r) { sf0[r] = 0.f; sf1[r] = 0.f; }                \
    __builtin_amdgcn_s_setprio(1);                                             \
    _Pragma("unroll")                                                          \
    for (int kf = 0; kf < 8; ++kf) {                                           \
        int sl_ = ((kf * 4 + g) ^ (c16 & 7)) * 8;                              \
        s16x8 ka0 = *(const s16x8*)&k_lds[(nt) & 1][(kp * 32 + c16) * 256 + sl_]; \
        sf0 = __builtin_amdgcn_mfma_f32_16x16x32_bf16(ka0, qf[kf], sf0, 0, 0, 0); \
        s16x8 ka1 = *(const s16x8*)&k_lds[(nt) & 1][(kp * 32 + 16 + c16) * 256 + sl_]; \
        sf1 = __builtin_amdgcn_mfma_f32_16x16x32_bf16(ka1, qf[kf], sf1, 0, 0, 0); \
    }                                                                          \
    __builtin_amdgcn_s_setprio(0);                                             \
    float rs = 0.f;                                                            \
    _Pragma("unroll")                                                          \
    for (int r = 0; r < 4; ++r) {                                              \
        float p0 = __expf(sf0[r] * 0.0625f);                                   \
        float p1 = __expf(sf1[r] * 0.0625f);                                   \
        sf0[r] = p0; sf1[r] = p1;                                              \
        rs += p0 + p1;                                                         \
    }                                                                          \
    rs += __shfl_xor(rs, 16);                                                  \
    rs += __shfl_xor(rs, 32);                                                  \
    l_r += rs;                                                                 \
    s16x8 pa;                                                                  \
    _Pragma("unroll")                                                          \
    for (int e = 0; e < 8; ++e)                                                \
        pa[e] = f2bf((e & 4) ? sf1[e & 3] : sf0[e & 3]);                       \
    *(s16x8*)&p_lds[(nt) & 1][qs][kp][lane * 8] = pa;                          \
} while (0)

    // prologue
    STAGE_K(0, 0);
    __syncthreads();               // K0 ready
    STAGE_K(1, 1);
    QKT_PHASE(0);                  // reads k[0], writes p[0]
    __syncthreads();               // K1 drained, p[0] visible

    for (int t = 0; t < 32; ++t) {
        const int buf = t & 1;
        const int kt0 = t * 64;

        // V(t) fragments direct from global (L2-hot), issued before QK^T
        s16x8 vf[8][2];
#pragma unroll
        for (int dt = 0; dt < 8; ++dt)
#pragma unroll
            for (int k2 = 0; k2 < 2; ++k2)
                vf[dt][k2] = *(const s16x8*)(Vt + vgbase
                    + (size_t)(dsl + dt * 16 + c16) * 2048 + kt0 + k2 * 32 + g * 8);

        if (t < 30) STAGE_K(buf, t + 2);       // k[(t+2)&1] == k[buf]
        if (t < 31) QKT_PHASE(t + 1);          // k[(t+1)&1], writes p[buf^1]

        // PV(t): 8 P reads (4 qs x 2 kp) + 64 MFMA with register V
#pragma unroll
        for (int q2 = 0; q2 < 4; ++q2) {
            s16x8 pa0 = *(const s16x8*)&p_lds[buf][q2][0][lane * 8];
            s16x8 pa1 = *(const s16x8*)&p_lds[buf][q2][1][lane * 8];
            __builtin_amdgcn_s_setprio(1);
#pragma unroll
            for (int dt = 0; dt < 8; ++dt) {
                oacc[q2 * 8 + dt] = __builtin_amdgcn_mfma_f32_16x16x32_bf16(
                    pa0, vf[dt][0], oacc[q2 * 8 + dt], 0, 0, 0);
                oacc[q2 * 8 + dt] = __builtin_amdgcn_mfma_f32_16x16x32_bf16(
                    pa1, vf[dt][1], oacc[q2 * 8 + dt], 0, 0, 0);
            }
            __builtin_amdgcn_s_setprio(0);
        }

        if (t < 31) __syncthreads();   // K DMA drained; p parity safe
    }

#undef STAGE_K
#undef QKT_PHASE

    // combine softmax denominators across the two key-half waves
    __syncthreads();
    if (lane < 16) l_sh[kp][qs * 16 + lane] = l_r;
    __syncthreads();

    // epilogue: O /= l, write bf16 in [b][h*16+ov][t][f] layout
    const int h = hb >> 1, b = hb & 1;
#pragma unroll
    for (int q2 = 0; q2 < 4; ++q2) {
        float li[4];
#pragma unroll
        for (int r = 0; r < 4; ++r) {
            int row = q2 * 16 + g * 4 + r;
            li[r] = 1.f / (l_sh[0][row] + l_sh[1][row]);
        }
#pragma unroll
        for (int dt = 0; dt < 8; ++dt) {
            int vcol = dsl + dt * 16 + c16;
            int cout = h * 16 + (vcol >> 6), ff = vcol & 63;
#pragma unroll
            for (int r = 0; r < 4; ++r) {
                int trow = t0 + q2 * 16 + g * 4 + r;
                Ob[(((size_t)b * 64 + cout) * 2048 + trow) * 64 + ff] =
                    f2bf(oacc[q2 * 8 + dt][r] * li[r]);
            }
        }
    }
}

// ---------------------------------------------------------------------------
// Kernel 4: output projection via MFMA + PReLU + LN(C,F) + residual
// ---------------------------------------------------------------------------
__global__ __launch_bounds__(256) void oproj_kernel(
    const short* __restrict__ Ob, const float* __restrict__ x,
    const short* __restrict__ Wpbf,
    const float* __restrict__ bp, const float* __restrict__ ap,
    const float* __restrict__ gp, const float* __restrict__ betp,
    float* __restrict__ out)
{
    const int t = blockIdx.x;
    const int b = blockIdx.y;
    const int tid = threadIdx.x;
    const int wid = tid >> 6, lane = tid & 63;
    const int g = lane >> 4, c16 = lane & 15;
    const int f_ = tid & 63, cg = tid >> 6;

    __shared__ __align__(16) short wp[64 * 64];
    __shared__ __align__(16) short os[64 * 64];
    __shared__ float zs[64 * 64];
    __shared__ float red[4][2];

#pragma unroll
    for (int j = 0; j < 2; ++j) {
        int i8 = tid + 256 * j;
        int row = i8 >> 3, cb = i8 & 7;
        s16x8 v = *(const s16x8*)(Wpbf + i8 * 8);
        *(s16x8*)&wp[row * 64 + ((cb ^ (row & 7)) * 8)] = v;
    }
#pragma unroll
    for (int it = 0; it < 2; ++it) {
        int cb = cg + 4 * it, c0 = cb * 8;
        s16x8 v;
#pragma unroll
        for (int i = 0; i < 8; ++i)
            v[i] = Ob[(((size_t)b * 64 + c0 + i) * 2048 + t) * 64 + f_];
        *(s16x8*)&os[f_ * 64 + ((cb ^ (f_ & 7)) * 8)] = v;
    }
    __syncthreads();

    const int f0 = wid * 16;
    s16x8 bfr[2];
#pragma unroll
    for (int kk = 0; kk < 2; ++kk)
        bfr[kk] = *(const s16x8*)&os[(f0 + c16) * 64 + (((kk * 4 + g) ^ (c16 & 7)) * 8)];

    const float ap0 = ap[0];
    f32x4 acc[4];
#pragma unroll
    for (int rt = 0; rt < 4; ++rt) {
#pragma unroll
        for (int r = 0; r < 4; ++r) acc[rt][r] = 0.f;
#pragma unroll
        for (int kk = 0; kk < 2; ++kk) {
            s16x8 a = *(const s16x8*)&wp[(rt * 16 + c16) * 64 + (((kk * 4 + g) ^ (c16 & 7)) * 8)];
            acc[rt] = __builtin_amdgcn_mfma_f32_16x16x32_bf16(a, bfr[kk], acc[rt], 0, 0, 0);
        }
    }

#pragma unroll
    for (int rt = 0; rt < 4; ++rt)
#pragma unroll
        for (int r = 0; r < 4; ++r) {
            int row = rt * 16 + g * 4 + r;
            float z = acc[rt][r] + bp[row];
            z = z >= 0.f ? z : ap0 * z;
            zs[row * 64 + f0 + c16] = z;
        }
    __syncthreads();

    float s = 0.f, ss = 0.f;
#pragma unroll
    for (int j = 0; j < 16; ++j) {
        float v = zs[(cg + 4 * j) * 64 + f_];
        s += v; ss += v * v;
    }
#pragma unroll
    for (int msk = 32; msk >= 1; msk >>= 1) {
        s  += __shfl_xor(s, msk);
        ss += __shfl_xor(ss, msk);
    }
    if (lane == 0) { red[wid][0] = s; red[wid][1] = ss; }
    __syncthreads();
    float ts  = red[0][0] + red[1][0] + red[2][0] + red[3][0];
    float tss = red[0][1] + red[1][1] + red[2][1] + red[3][1];
    float mean = ts * (1.f / 4096.f);
    float rstd = rsqrtf(tss * (1.f / 4096.f) - mean * mean + EPS_);

#pragma unroll
    for (int j = 0; j < 16; ++j) {
        int row = cg + 4 * j;
        size_t idx = (((size_t)b * 64 + row) * 2048 + t) * 64 + f_;
        out[idx] = (zs[row * 64 + f_] - mean) * rstd * gp[row * 64 + f_]
                 + betp[row * 64 + f_] + x[idx];
    }
}

// ---------------------------------------------------------------------------
extern "C" void kernel_launch(void* const* d_in, const int* in_sizes, int n_in,
                              void* d_out, int out_size, void* d_ws, size_t ws_size,
                              hipStream_t stream)
{
    const float* x    = (const float*)d_in[0];
    const float* Wq   = (const float*)d_in[1];
    const float* bq   = (const float*)d_in[2];
    const float* aq   = (const float*)d_in[3];
    const float* gq   = (const float*)d_in[4];
    const float* betq = (const float*)d_in[5];
    const float* Wk   = (const float*)d_in[6];
    const float* bk   = (const float*)d_in[7];
    const float* ak   = (const float*)d_in[8];
    const float* gk   = (const float*)d_in[9];
    const float* betk = (const float*)d_in[10];
    const float* Wv   = (const float*)d_in[11];
    const float* bv   = (const float*)d_in[12];
    const float* av   = (const float*)d_in[13];
    const float* gv   = (const float*)d_in[14];
    const float* betv = (const float*)d_in[15];
    const float* Wp   = (const float*)d_in[16];
    const float* bp   = (const float*)d_in[17];
    const float* ap   = (const float*)d_in[18];
    const float* gp   = (const float*)d_in[19];
    const float* betp = (const float*)d_in[20];

    short* Qb   = (short*)d_ws;
    short* Kb   = Qb   + (size_t)8 * 2048 * 256;
    short* Vrm  = Kb   + (size_t)8 * 2048 * 256;
    short* Vt   = Vrm  + (size_t)8 * 2048 * 1024;
    short* Obuf = Vt   + (size_t)8 * 2048 * 1024;
    short* Wbf  = Obuf + (size_t)8 * 2048 * 1024;
    short* Wpbf = Wbf  + 96 * 64;

    prep_kernel<<<40, 256, 0, stream>>>(Wq, Wk, Wv, Wp, Wbf, Wpbf);
    qkv_kernel<<<dim3(2048, 2), 256, 0, stream>>>(x, Wbf,
        bq, aq, gq, betq, bk, ak, gk, betk, bv, av, gv, betv, Qb, Kb, Vrm);
    vtrans_kernel<<<dim3(32, 16, 8), 256, 0, stream>>>(Vrm, Vt);
    attn_kernel<<<dim3(8, 32), 512, 0, stream>>>(Qb, Kb, Vt, Obuf);
    oproj_kernel<<<dim3(2048, 2), 256, 0, stream>>>(Obuf, x, Wpbf,
        bp, ap, gp, betp, (float*)d_out);
}

// Round 15
// 235.212 us; speedup vs baseline: 1.4130x; 1.4130x over previous
//
#include <hip/hip_runtime.h>

#define EPS_ 1e-5f

typedef float f32x4 __attribute__((ext_vector_type(4)));
typedef short s16x8 __attribute__((ext_vector_type(8)));

static __device__ __forceinline__ short f2bf(float f) {
    unsigned u = __float_as_uint(f);
    unsigned r = (u + 0x7FFFu + ((u >> 16) & 1u)) >> 16;
    return (short)r;
}
static __device__ __forceinline__ float bf2f(short s) {
    return __uint_as_float(((unsigned)(unsigned short)s) << 16);
}

// async global->LDS, 16B per lane, wave-uniform LDS base
static __device__ __forceinline__ void gload16(const short* g, short* l) {
    __builtin_amdgcn_global_load_lds(
        (const __attribute__((address_space(1))) unsigned int*)g,
        (__attribute__((address_space(3))) unsigned int*)l, 16, 0, 0);
}

// ---------------------------------------------------------------------------
// Kernel 0: convert weight stacks to bf16 once.
// ---------------------------------------------------------------------------
__global__ __launch_bounds__(256) void prep_kernel(
    const float* __restrict__ Wq, const float* __restrict__ Wk,
    const float* __restrict__ Wv, const float* __restrict__ Wp,
    short* __restrict__ Wbf, short* __restrict__ Wpbf)
{
    int i = blockIdx.x * 256 + threadIdx.x;
    if (i < 6144) {
        float v = (i < 1024) ? Wq[i] : (i < 2048 ? Wk[i - 1024] : Wv[i - 2048]);
        Wbf[i] = f2bf(v);
    } else if (i < 6144 + 4096) {
        Wpbf[i - 6144] = f2bf(Wp[i - 6144]);
    }
}

// ---------------------------------------------------------------------------
// Kernel 1: QKV projection via MFMA + PReLU + LN(chan,freq), write bf16.
// ---------------------------------------------------------------------------
__global__ __launch_bounds__(256) void qkv_kernel(
    const float* __restrict__ x, const short* __restrict__ Wbf,
    const float* __restrict__ bq, const float* __restrict__ aq,
    const float* __restrict__ gq, const float* __restrict__ betq,
    const float* __restrict__ bk, const float* __restrict__ ak,
    const float* __restrict__ gk, const float* __restrict__ betk,
    const float* __restrict__ bv, const float* __restrict__ av,
    const float* __restrict__ gv, const float* __restrict__ betv,
    short* __restrict__ Qo, short* __restrict__ Ko, short* __restrict__ Vo)
{
    const int t = blockIdx.x;
    const int b = blockIdx.y;
    const int tid = threadIdx.x;
    const int wid = tid >> 6, lane = tid & 63;
    const int g = lane >> 4, c16 = lane & 15;
    const int f_ = tid & 63, cg = tid >> 6;

    __shared__ __align__(16) short wlds[96 * 64];
    __shared__ __align__(16) short xs[64 * 64];
    __shared__ float zs[96 * 64];
    __shared__ float stats[12][2];
    __shared__ float bias_l[96], alpha_l[96];

#pragma unroll
    for (int j = 0; j < 3; ++j) {
        int i8 = tid + 256 * j;
        int row = i8 >> 3, cb = i8 & 7;
        s16x8 v = *(const s16x8*)(Wbf + i8 * 8);
        *(s16x8*)&wlds[row * 64 + ((cb ^ (row & 7)) * 8)] = v;
    }
    if (tid < 96) {
        int row = tid; float bias, al;
        if (row < 16)      { bias = bq[row];      al = aq[row >> 2]; }
        else if (row < 32) { bias = bk[row - 16]; al = ak[(row - 16) >> 2]; }
        else               { bias = bv[row - 32]; al = av[(row - 32) >> 4]; }
        bias_l[row] = bias; alpha_l[row] = al;
    }
#pragma unroll
    for (int it = 0; it < 2; ++it) {
        int cb = cg + 4 * it, c0 = cb * 8;
        s16x8 v;
#pragma unroll
        for (int i = 0; i < 8; ++i)
            v[i] = f2bf(x[(((size_t)b * 64 + c0 + i) * 2048 + t) * 64 + f_]);
        *(s16x8*)&xs[f_ * 64 + ((cb ^ (f_ & 7)) * 8)] = v;
    }
    __syncthreads();

    const int f0 = wid * 16;
    s16x8 bfr[2];
#pragma unroll
    for (int kk = 0; kk < 2; ++kk)
        bfr[kk] = *(const s16x8*)&xs[(f0 + c16) * 64 + (((kk * 4 + g) ^ (c16 & 7)) * 8)];

    f32x4 acc[6];
#pragma unroll
    for (int rt = 0; rt < 6; ++rt) {
#pragma unroll
        for (int r = 0; r < 4; ++r) acc[rt][r] = 0.f;
#pragma unroll
        for (int kk = 0; kk < 2; ++kk) {
            s16x8 a = *(const s16x8*)&wlds[(rt * 16 + c16) * 64 + (((kk * 4 + g) ^ (c16 & 7)) * 8)];
            acc[rt] = __builtin_amdgcn_mfma_f32_16x16x32_bf16(a, bfr[kk], acc[rt], 0, 0, 0);
        }
    }

#pragma unroll
    for (int rt = 0; rt < 6; ++rt)
#pragma unroll
        for (int r = 0; r < 4; ++r) {
            int row = rt * 16 + g * 4 + r;
            float z = acc[rt][r] + bias_l[row];
            z = z >= 0.f ? z : alpha_l[row] * z;
            zs[row * 64 + f0 + c16] = z;
        }
    __syncthreads();

#pragma unroll
    for (int gi = 0; gi < 3; ++gi) {
        int grp = wid * 3 + gi;
        int base_row, n;
        if (grp < 4)      { base_row = grp * 4;             n = 256; }
        else if (grp < 8) { base_row = 16 + (grp - 4) * 4;  n = 256; }
        else              { base_row = 32 + (grp - 8) * 16; n = 1024; }
        int cnt = n >> 6;
        float s = 0.f, ss = 0.f;
        for (int i = 0; i < cnt; ++i) {
            float v = zs[(base_row + i) * 64 + lane];
            s += v; ss += v * v;
        }
#pragma unroll
        for (int msk = 32; msk >= 1; msk >>= 1) {
            s  += __shfl_xor(s, msk);
            ss += __shfl_xor(ss, msk);
        }
        if (lane == 0) {
            float mean = s / n;
            float var = ss / n - mean * mean;
            stats[grp][0] = mean;
            stats[grp][1] = rsqrtf(var + EPS_);
        }
    }
    __syncthreads();

#pragma unroll
    for (int j = 0; j < 24; ++j) {
        int row = cg + 4 * j;
        float zv = zs[row * 64 + f_];
        if (row < 16) {
            int grp = row >> 2;
            float val = (zv - stats[grp][0]) * stats[grp][1];
            val = val * gq[row * 64 + f_] + betq[row * 64 + f_];
            int h = row >> 2, o = row & 3;
            Qo[(((size_t)(h * 2 + b)) * 2048 + t) * 256 + o * 64 + f_] = f2bf(val);
        } else if (row < 32) {
            int rr = row - 16, grp = 4 + (rr >> 2);
            float val = (zv - stats[grp][0]) * stats[grp][1];
            val = val * gk[rr * 64 + f_] + betk[rr * 64 + f_];
            int h = rr >> 2, o = rr & 3;
            Ko[(((size_t)(h * 2 + b)) * 2048 + t) * 256 + o * 64 + f_] = f2bf(val);
        } else {
            int rr = row - 32, grp = 8 + (rr >> 4);
            float val = (zv - stats[grp][0]) * stats[grp][1];
            val = val * gv[rr * 64 + f_] + betv[rr * 64 + f_];
            int h = rr >> 4, ov = rr & 15;
            Vo[(((size_t)(h * 2 + b)) * 2048 + t) * 1024 + ov * 64 + f_] = f2bf(val);
        }
    }
}

// ---------------------------------------------------------------------------
// Kernel 2: V row-major [hb][t][d] -> V^T [hb][d][pi(t)] where pi relabels
// keys within each 32-aligned t-block so the in-register P from swapped
// QK^T feeds PV's A-operand with zero cross-lane movement.
// k' bits (b4 b3 b2 b1 b0) -> phys = b2*16 + b4*8 + b3*4 + b1b0.
// ---------------------------------------------------------------------------
__global__ __launch_bounds__(256) void vtrans_kernel(
    const short* __restrict__ Vrm, short* __restrict__ Vt)
{
    const int t0 = blockIdx.x * 64;
    const int d0 = blockIdx.y * 64;
    const int hb = blockIdx.z;
    const int tid = threadIdx.x;
    __shared__ __align__(16) short tile[64 * 72];

#pragma unroll
    for (int k = 0; k < 2; ++k) {
        int q = tid + 256 * k;
        int row = q >> 3, slot = q & 7;
        s16x8 v = *(const s16x8*)(Vrm + ((size_t)hb * 2048 + t0 + row) * 1024 + d0 + slot * 8);
        *(s16x8*)&tile[row * 72 + slot * 8] = v;
    }
    __syncthreads();
#pragma unroll
    for (int k = 0; k < 2; ++k) {
        int q = tid + 256 * k;
        int drow = q >> 3, tslot = q & 7;
        s16x8 v;
#pragma unroll
        for (int i = 0; i < 8; ++i) {
            int c = tslot * 8 + i;
            int cl = c & 31;
            int src = (c & 32) + ((cl >> 2) & 1) * 16 + ((cl >> 4) & 1) * 8
                    + ((cl >> 3) & 1) * 4 + (cl & 3);
            v[i] = tile[src * 72 + drow];
        }
        *(s16x8*)(Vt + ((size_t)hb * 1024 + d0 + drow) * 2048 + t0 + tslot * 8) = v;
    }
}

// ---------------------------------------------------------------------------
// Kernel 3: flash attention — r13 structure + counted-vmcnt barriers (T4).
// Grid (8 hb, 16 qt, 2 dh) = 256 blocks, 512 thr (8 waves). QBLK=128,
// KBLK=32, 64 k-tiles.
// K quad-buffered (staged 3 tiles ahead); V+P double-buffered.
// Per-tile barrier = s_waitcnt vmcnt(4) lgkmcnt(0) + s_barrier:
// the newest 4 VMEM ops (K(t+3) DMA, issued LAST in the tile) stay in
// flight across the barrier; K(t+2) and V(t+1) are guaranteed complete.
// Tail tiles (t>=61, no K issued) fall back to vmcnt(0).
// LDS: K 4x16K + V 2x32K + P 2x8K = 144 KB.
// ---------------------------------------------------------------------------
__global__ __launch_bounds__(512, 2) void attn_kernel(
    const short* __restrict__ Qg, const short* __restrict__ Kg,
    const short* __restrict__ Vt, short* __restrict__ Ob)
{
    const int hb = blockIdx.x;
    const int qt = blockIdx.y;     // 0..15
    const int dh = blockIdx.z;     // 0..1
    const int t0 = qt * 128;
    const int tid = threadIdx.x;
    const int lane = tid & 63;
    const int wid = tid >> 6;      // q-stripe (QK^T) / d-slice (PV)
    const int g = lane >> 4, c16 = lane & 15;

    __shared__ __align__(16) short k_lds[4][32 * 256];   // 4x16 KB
    __shared__ __align__(16) short v_lds[2][512 * 32];   // 2x32 KB
    __shared__ __align__(16) short p_lds[2][8][512];     // 2x8 KB
    __shared__ float l_sh[128];

    const size_t kgbase = (size_t)hb * 2048 * 256;
    const size_t vgbase = ((size_t)hb * 1024 + dh * 512) * 2048;
    const int dsl = wid * 64;      // this wave's d-slice within the 512 half

    // Q B-fragments for q-stripe wid (16 rows x 256 d), persistent
    const size_t qrow = (size_t)hb * 2048 + t0 + wid * 16 + c16;
    s16x8 qf[8];
#pragma unroll
    for (int kf = 0; kf < 8; ++kf)
        qf[kf] = *(const s16x8*)(Qg + qrow * 256 + kf * 32 + g * 8);

    f32x4 oacc[32];                // [qs 0..7][dt 0..3]
#pragma unroll
    for (int i = 0; i < 32; ++i)
#pragma unroll
        for (int r = 0; r < 4; ++r) oacc[i][r] = 0.f;

    float l_r = 0.f;               // softmax denom for q = wid*16 + c16

#define STAGE_K(buf, kt) do {                                                  \
    _Pragma("unroll")                                                          \
    for (int j_ = 0; j_ < 2; ++j_) {                                           \
        int c_ = tid + 512 * j_;                                               \
        int row_ = c_ >> 5, sp_ = c_ & 31;                                     \
        int sl_ = sp_ ^ (row_ & 7);                                            \
        gload16(Kg + kgbase + (size_t)((kt) * 32 + row_) * 256 + sl_ * 8,      \
                &k_lds[buf][c_ * 8]);                                          \
    }                                                                          \
} while (0)

#define STAGE_V(buf, kt) do {                                                  \
    _Pragma("unroll")                                                          \
    for (int j_ = 0; j_ < 4; ++j_) {                                           \
        int c_ = tid + 512 * j_;                                               \
        int row_ = c_ >> 2, sp_ = c_ & 3;                                      \
        int sl_ = sp_ ^ ((row_ >> 1) & 3);                                     \
        gload16(Vt + vgbase + (size_t)row_ * 2048 + (kt) * 32 + sl_ * 8,       \
                &v_lds[buf][c_ * 8]);                                          \
    }                                                                          \
} while (0)

    // QK^T for tile nt (swapped): lane ends with P[key][q=c16] for 32 keys,
    // packed via pi into pa (PV A-operand layout), one b128 write to p_lds.
#define QKT_PHASE(nt) do {                                                     \
    f32x4 sf0, sf1;                                                            \
    _Pragma("unroll")                                                          \
    for (int r = 0; r < 4; ++r) { sf0[r] = 0.f; sf1[r] = 0.f; }                \
    __builtin_amdgcn_s_setprio(1);                                             \
    _Pragma("unroll")                                                          \
    for (int kf = 0; kf < 8; ++kf) {                                           \
        int sl_ = ((kf * 4 + g) ^ (c16 & 7)) * 8;                              \
        s16x8 ka0 = *(const s16x8*)&k_lds[(nt) & 3][c16 * 256 + sl_];          \
        sf0 = __builtin_amdgcn_mfma_f32_16x16x32_bf16(ka0, qf[kf], sf0, 0, 0, 0); \
        s16x8 ka1 = *(const s16x8*)&k_lds[(nt) & 3][(16 + c16) * 256 + sl_];   \
        sf1 = __builtin_amdgcn_mfma_f32_16x16x32_bf16(ka1, qf[kf], sf1, 0, 0, 0); \
    }                                                                          \
    __builtin_amdgcn_s_setprio(0);                                             \
    float rs = 0.f;                                                            \
    _Pragma("unroll")                                                          \
    for (int r = 0; r < 4; ++r) {                                              \
        float p0 = __expf(sf0[r] * 0.0625f);                                   \
        float p1 = __expf(sf1[r] * 0.0625f);                                   \
        sf0[r] = p0; sf1[r] = p1;                                              \
        rs += p0 + p1;                                                         \
    }                                                                          \
    rs += __shfl_xor(rs, 16);                                                  \
    rs += __shfl_xor(rs, 32);                                                  \
    l_r += rs;                                                                 \
    s16x8 pa;                                                                  \
    _Pragma("unroll")                                                          \
    for (int e = 0; e < 8; ++e)                                                \
        pa[e] = f2bf((e & 4) ? sf1[e & 3] : sf0[e & 3]);                       \
    *(s16x8*)&p_lds[(nt) & 1][wid][lane * 8] = pa;                             \
} while (0)

    // counted barrier: newest 4 VMEM ops (K DMA) float across
#define TILE_BARRIER4() do {                                                   \
    __builtin_amdgcn_sched_barrier(0);                                         \
    asm volatile("s_waitcnt vmcnt(4) lgkmcnt(0)" ::: "memory");                \
    __builtin_amdgcn_sched_barrier(0);                                         \
    __builtin_amdgcn_s_barrier();                                              \
} while (0)
#define TILE_BARRIER0() do {                                                   \
    __builtin_amdgcn_sched_barrier(0);                                         \
    asm volatile("s_waitcnt vmcnt(0) lgkmcnt(0)" ::: "memory");                \
    __builtin_amdgcn_sched_barrier(0);                                         \
    __builtin_amdgcn_s_barrier();                                              \
} while (0)

    // prologue: K0,K1,V0 staged and drained; then K2 issued (floats), QKT(0)
    STAGE_K(0, 0);
    STAGE_K(1, 1);
    STAGE_V(0, 0);
    __syncthreads();               // full drain: K0,K1,V0 ready
    STAGE_K(2, 2);                 // in flight across next barrier
    QKT_PHASE(0);                  // reads k[0], writes p[0]
    __builtin_amdgcn_sched_barrier(0);
    asm volatile("s_waitcnt vmcnt(4) lgkmcnt(0)" ::: "memory");   // K2 floats
    __builtin_amdgcn_sched_barrier(0);
    __builtin_amdgcn_s_barrier();  // p[0] visible

    for (int t = 0; t < 64; ++t) {
        const int buf = t & 1;

        if (t < 63) STAGE_V(buf ^ 1, t + 1);   // issued FIRST (must retire)
        if (t < 61) STAGE_K((t + 3) & 3, t + 3);  // issued LAST (floats)
        if (t < 63) QKT_PHASE(t + 1);          // k[(t+1)&3], writes p[buf^1]

        // PV(t): 4 V B-frags (reused across 8 q-subtiles) + 8 P A-frags
        s16x8 vb[4];
#pragma unroll
        for (int dt = 0; dt < 4; ++dt) {
            int rowv = dsl + dt * 16 + c16;
            vb[dt] = *(const s16x8*)&v_lds[buf][rowv * 32 + ((g ^ ((c16 >> 1) & 3)) * 8)];
        }
        __builtin_amdgcn_s_setprio(1);
#pragma unroll
        for (int qs = 0; qs < 8; ++qs) {
            s16x8 pa = *(const s16x8*)&p_lds[buf][qs][lane * 8];
#pragma unroll
            for (int dt = 0; dt < 4; ++dt)
                oacc[qs * 4 + dt] = __builtin_amdgcn_mfma_f32_16x16x32_bf16(
                    pa, vb[dt], oacc[qs * 4 + dt], 0, 0, 0);
        }
        __builtin_amdgcn_s_setprio(0);

        if (t < 61)      TILE_BARRIER4();
        else if (t < 63) TILE_BARRIER0();
    }

#undef STAGE_K
#undef STAGE_V
#undef QKT_PHASE
#undef TILE_BARRIER4
#undef TILE_BARRIER0

    // share softmax denominators (wave wid owns q-rows wid*16 + 0..15)
    __syncthreads();
    if (lane < 16) l_sh[wid * 16 + lane] = l_r;
    __syncthreads();

    // epilogue: O /= l, write bf16 in [b][h*16+ov][t][f] layout
    const int h = hb >> 1, b = hb & 1;
#pragma unroll
    for (int qs = 0; qs < 8; ++qs) {
        float li[4];
#pragma unroll
        for (int r = 0; r < 4; ++r)
            li[r] = 1.f / l_sh[qs * 16 + g * 4 + r];
#pragma unroll
        for (int dt = 0; dt < 4; ++dt) {
            int vcol = dh * 512 + dsl + dt * 16 + c16;
            int cout = h * 16 + (vcol >> 6), ff = vcol & 63;
#pragma unroll
            for (int r = 0; r < 4; ++r) {
                int trow = t0 + qs * 16 + g * 4 + r;
                Ob[(((size_t)b * 64 + cout) * 2048 + trow) * 64 + ff] =
                    f2bf(oacc[qs * 4 + dt][r] * li[r]);
            }
        }
    }
}

// ---------------------------------------------------------------------------
// Kernel 4: output projection via MFMA + PReLU + LN(C,F) + residual
// ---------------------------------------------------------------------------
__global__ __launch_bounds__(256) void oproj_kernel(
    const short* __restrict__ Ob, const float* __restrict__ x,
    const short* __restrict__ Wpbf,
    const float* __restrict__ bp, const float* __restrict__ ap,
    const float* __restrict__ gp, const float* __restrict__ betp,
    float* __restrict__ out)
{
    const int t = blockIdx.x;
    const int b = blockIdx.y;
    const int tid = threadIdx.x;
    const int wid = tid >> 6, lane = tid & 63;
    const int g = lane >> 4, c16 = lane & 15;
    const int f_ = tid & 63, cg = tid >> 6;

    __shared__ __align__(16) short wp[64 * 64];
    __shared__ __align__(16) short os[64 * 64];
    __shared__ float zs[64 * 64];
    __shared__ float red[4][2];

#pragma unroll
    for (int j = 0; j < 2; ++j) {
        int i8 = tid + 256 * j;
        int row = i8 >> 3, cb = i8 & 7;
        s16x8 v = *(const s16x8*)(Wpbf + i8 * 8);
        *(s16x8*)&wp[row * 64 + ((cb ^ (row & 7)) * 8)] = v;
    }
#pragma unroll
    for (int it = 0; it < 2; ++it) {
        int cb = cg + 4 * it, c0 = cb * 8;
        s16x8 v;
#pragma unroll
        for (int i = 0; i < 8; ++i)
            v[i] = Ob[(((size_t)b * 64 + c0 + i) * 2048 + t) * 64 + f_];
        *(s16x8*)&os[f_ * 64 + ((cb ^ (f_ & 7)) * 8)] = v;
    }
    __syncthreads();

    const int f0 = wid * 16;
    s16x8 bfr[2];
#pragma unroll
    for (int kk = 0; kk < 2; ++kk)
        bfr[kk] = *(const s16x8*)&os[(f0 + c16) * 64 + (((kk * 4 + g) ^ (c16 & 7)) * 8)];

    const float ap0 = ap[0];
    f32x4 acc[4];
#pragma unroll
    for (int rt = 0; rt < 4; ++rt) {
#pragma unroll
        for (int r = 0; r < 4; ++r) acc[rt][r] = 0.f;
#pragma unroll
        for (int kk = 0; kk < 2; ++kk) {
            s16x8 a = *(const s16x8*)&wp[(rt * 16 + c16) * 64 + (((kk * 4 + g) ^ (c16 & 7)) * 8)];
            acc[rt] = __builtin_amdgcn_mfma_f32_16x16x32_bf16(a, bfr[kk], acc[rt], 0, 0, 0);
        }
    }

#pragma unroll
    for (int rt = 0; rt < 4; ++rt)
#pragma unroll
        for (int r = 0; r < 4; ++r) {
            int row = rt * 16 + g * 4 + r;
            float z = acc[rt][r] + bp[row];
            z = z >= 0.f ? z : ap0 * z;
            zs[row * 64 + f0 + c16] = z;
        }
    __syncthreads();

    float s = 0.f, ss = 0.f;
#pragma unroll
    for (int j = 0; j < 16; ++j) {
        float v = zs[(cg + 4 * j) * 64 + f_];
        s += v; ss += v * v;
    }
#pragma unroll
    for (int msk = 32; msk >= 1; msk >>= 1) {
        s  += __shfl_xor(s, msk);
        ss += __shfl_xor(ss, msk);
    }
    if (lane == 0) { red[wid][0] = s; red[wid][1] = ss; }
    __syncthreads();
    float ts  = red[0][0] + red[1][0] + red[2][0] + red[3][0];
    float tss = red[0][1] + red[1][1] + red[2][1] + red[3][1];
    float mean = ts * (1.f / 4096.f);
    float rstd = rsqrtf(tss * (1.f / 4096.f) - mean * mean + EPS_);

#pragma unroll
    for (int j = 0; j < 16; ++j) {
        int row = cg + 4 * j;
        size_t idx = (((size_t)b * 64 + row) * 2048 + t) * 64 + f_;
        out[idx] = (zs[row * 64 + f_] - mean) * rstd * gp[row * 64 + f_]
                 + betp[row * 64 + f_] + x[idx];
    }
}

// ---------------------------------------------------------------------------
extern "C" void kernel_launch(void* const* d_in, const int* in_sizes, int n_in,
                              void* d_out, int out_size, void* d_ws, size_t ws_size,
                              hipStream_t stream)
{
    const float* x    = (const float*)d_in[0];
    const float* Wq   = (const float*)d_in[1];
    const float* bq   = (const float*)d_in[2];
    const float* aq   = (const float*)d_in[3];
    const float* gq   = (const float*)d_in[4];
    const float* betq = (const float*)d_in[5];
    const float* Wk   = (const float*)d_in[6];
    const float* bk   = (const float*)d_in[7];
    const float* ak   = (const float*)d_in[8];
    const float* gk   = (const float*)d_in[9];
    const float* betk = (const float*)d_in[10];
    const float* Wv   = (const float*)d_in[11];
    const float* bv   = (const float*)d_in[12];
    const float* av   = (const float*)d_in[13];
    const float* gv   = (const float*)d_in[14];
    const float* betv = (const float*)d_in[15];
    const float* Wp   = (const float*)d_in[16];
    const float* bp   = (const float*)d_in[17];
    const float* ap   = (const float*)d_in[18];
    const float* gp   = (const float*)d_in[19];
    const float* betp = (const float*)d_in[20];

    short* Qb   = (short*)d_ws;
    short* Kb   = Qb   + (size_t)8 * 2048 * 256;
    short* Vrm  = Kb   + (size_t)8 * 2048 * 256;
    short* Vt   = Vrm  + (size_t)8 * 2048 * 1024;
    short* Obuf = Vt   + (size_t)8 * 2048 * 1024;
    short* Wbf  = Obuf + (size_t)8 * 2048 * 1024;
    short* Wpbf = Wbf  + 96 * 64;

    prep_kernel<<<40, 256, 0, stream>>>(Wq, Wk, Wv, Wp, Wbf, Wpbf);
    qkv_kernel<<<dim3(2048, 2), 256, 0, stream>>>(x, Wbf,
        bq, aq, gq, betq, bk, ak, gk, betk, bv, av, gv, betv, Qb, Kb, Vrm);
    vtrans_kernel<<<dim3(32, 16, 8), 256, 0, stream>>>(Vrm, Vt);
    attn_kernel<<<dim3(8, 16, 2), 512, 0, stream>>>(Qb, Kb, Vt, Obuf);
    oproj_kernel<<<dim3(2048, 2), 256, 0, stream>>>(Obuf, x, Wpbf,
        bp, ap, gp, betp, (float*)d_out);
}

// Round 16
// 233.638 us; speedup vs baseline: 1.4226x; 1.0067x over previous
//
#include <hip/hip_runtime.h>

#define EPS_ 1e-5f

typedef float f32x4 __attribute__((ext_vector_type(4)));
typedef short s16x4 __attribute__((ext_vector_type(4)));
typedef short s16x8 __attribute__((ext_vector_type(8)));

static __device__ __forceinline__ short f2bf(float f) {
    unsigned u = __float_as_uint(f);
    unsigned r = (u + 0x7FFFu + ((u >> 16) & 1u)) >> 16;
    return (short)r;
}
static __device__ __forceinline__ float bf2f(short s) {
    return __uint_as_float(((unsigned)(unsigned short)s) << 16);
}

// async global->LDS, 16B per lane, wave-uniform LDS base
static __device__ __forceinline__ void gload16(const short* g, short* l) {
    __builtin_amdgcn_global_load_lds(
        (const __attribute__((address_space(1))) unsigned int*)g,
        (__attribute__((address_space(3))) unsigned int*)l, 16, 0, 0);
}

// ---------------------------------------------------------------------------
// Kernel 1: QKV projection via MFMA + PReLU + LN(chan,freq), write bf16.
// (weight bf16 conversion fused: stages directly from fp32 W)
// ---------------------------------------------------------------------------
__global__ __launch_bounds__(256) void qkv_kernel(
    const float* __restrict__ x,
    const float* __restrict__ Wq, const float* __restrict__ Wk,
    const float* __restrict__ Wv,
    const float* __restrict__ bq, const float* __restrict__ aq,
    const float* __restrict__ gq, const float* __restrict__ betq,
    const float* __restrict__ bk, const float* __restrict__ ak,
    const float* __restrict__ gk, const float* __restrict__ betk,
    const float* __restrict__ bv, const float* __restrict__ av,
    const float* __restrict__ gv, const float* __restrict__ betv,
    short* __restrict__ Qo, short* __restrict__ Ko, short* __restrict__ Vo)
{
    const int t = blockIdx.x;
    const int b = blockIdx.y;
    const int tid = threadIdx.x;
    const int wid = tid >> 6, lane = tid & 63;
    const int g = lane >> 4, c16 = lane & 15;
    const int f_ = tid & 63, cg = tid >> 6;

    __shared__ __align__(16) short wlds[96 * 64];
    __shared__ __align__(16) short xs[64 * 64];
    __shared__ float zs[96 * 64];
    __shared__ float stats[12][2];
    __shared__ float bias_l[96], alpha_l[96];

    // stage weights from fp32 (bf16-convert inline), swizzled 16B slots
#pragma unroll
    for (int j = 0; j < 3; ++j) {
        int i8 = tid + 256 * j;
        int row = i8 >> 3, cb = i8 & 7;
        int idx = i8 * 8;
        const float* src = (idx < 1024) ? (Wq + idx)
                         : (idx < 2048) ? (Wk + idx - 1024) : (Wv + idx - 2048);
        f32x4 a0 = *(const f32x4*)src;
        f32x4 a1 = *(const f32x4*)(src + 4);
        s16x8 v;
#pragma unroll
        for (int i = 0; i < 4; ++i) { v[i] = f2bf(a0[i]); v[4 + i] = f2bf(a1[i]); }
        *(s16x8*)&wlds[row * 64 + ((cb ^ (row & 7)) * 8)] = v;
    }
    if (tid < 96) {
        int row = tid; float bias, al;
        if (row < 16)      { bias = bq[row];      al = aq[row >> 2]; }
        else if (row < 32) { bias = bk[row - 16]; al = ak[(row - 16) >> 2]; }
        else               { bias = bv[row - 32]; al = av[(row - 32) >> 4]; }
        bias_l[row] = bias; alpha_l[row] = al;
    }
#pragma unroll
    for (int it = 0; it < 2; ++it) {
        int cb = cg + 4 * it, c0 = cb * 8;
        s16x8 v;
#pragma unroll
        for (int i = 0; i < 8; ++i)
            v[i] = f2bf(x[(((size_t)b * 64 + c0 + i) * 2048 + t) * 64 + f_]);
        *(s16x8*)&xs[f_ * 64 + ((cb ^ (f_ & 7)) * 8)] = v;
    }
    __syncthreads();

    const int f0 = wid * 16;
    s16x8 bfr[2];
#pragma unroll
    for (int kk = 0; kk < 2; ++kk)
        bfr[kk] = *(const s16x8*)&xs[(f0 + c16) * 64 + (((kk * 4 + g) ^ (c16 & 7)) * 8)];

    f32x4 acc[6];
#pragma unroll
    for (int rt = 0; rt < 6; ++rt) {
#pragma unroll
        for (int r = 0; r < 4; ++r) acc[rt][r] = 0.f;
#pragma unroll
        for (int kk = 0; kk < 2; ++kk) {
            s16x8 a = *(const s16x8*)&wlds[(rt * 16 + c16) * 64 + (((kk * 4 + g) ^ (c16 & 7)) * 8)];
            acc[rt] = __builtin_amdgcn_mfma_f32_16x16x32_bf16(a, bfr[kk], acc[rt], 0, 0, 0);
        }
    }

#pragma unroll
    for (int rt = 0; rt < 6; ++rt)
#pragma unroll
        for (int r = 0; r < 4; ++r) {
            int row = rt * 16 + g * 4 + r;
            float z = acc[rt][r] + bias_l[row];
            z = z >= 0.f ? z : alpha_l[row] * z;
            zs[row * 64 + f0 + c16] = z;
        }
    __syncthreads();

#pragma unroll
    for (int gi = 0; gi < 3; ++gi) {
        int grp = wid * 3 + gi;
        int base_row, n;
        if (grp < 4)      { base_row = grp * 4;             n = 256; }
        else if (grp < 8) { base_row = 16 + (grp - 4) * 4;  n = 256; }
        else              { base_row = 32 + (grp - 8) * 16; n = 1024; }
        int cnt = n >> 6;
        float s = 0.f, ss = 0.f;
        for (int i = 0; i < cnt; ++i) {
            float v = zs[(base_row + i) * 64 + lane];
            s += v; ss += v * v;
        }
#pragma unroll
        for (int msk = 32; msk >= 1; msk >>= 1) {
            s  += __shfl_xor(s, msk);
            ss += __shfl_xor(ss, msk);
        }
        if (lane == 0) {
            float mean = s / n;
            float var = ss / n - mean * mean;
            stats[grp][0] = mean;
            stats[grp][1] = rsqrtf(var + EPS_);
        }
    }
    __syncthreads();

#pragma unroll
    for (int j = 0; j < 24; ++j) {
        int row = cg + 4 * j;
        float zv = zs[row * 64 + f_];
        if (row < 16) {
            int grp = row >> 2;
            float val = (zv - stats[grp][0]) * stats[grp][1];
            val = val * gq[row * 64 + f_] + betq[row * 64 + f_];
            int h = row >> 2, o = row & 3;
            Qo[(((size_t)(h * 2 + b)) * 2048 + t) * 256 + o * 64 + f_] = f2bf(val);
        } else if (row < 32) {
            int rr = row - 16, grp = 4 + (rr >> 2);
            float val = (zv - stats[grp][0]) * stats[grp][1];
            val = val * gk[rr * 64 + f_] + betk[rr * 64 + f_];
            int h = rr >> 2, o = rr & 3;
            Ko[(((size_t)(h * 2 + b)) * 2048 + t) * 256 + o * 64 + f_] = f2bf(val);
        } else {
            int rr = row - 32, grp = 8 + (rr >> 4);
            float val = (zv - stats[grp][0]) * stats[grp][1];
            val = val * gv[rr * 64 + f_] + betv[rr * 64 + f_];
            int h = rr >> 4, ov = rr & 15;
            Vo[(((size_t)(h * 2 + b)) * 2048 + t) * 1024 + ov * 64 + f_] = f2bf(val);
        }
    }
}

// ---------------------------------------------------------------------------
// Kernel 2: V row-major [hb][t][d] -> V^T [hb][d][pi(t)] where pi relabels
// keys within each 32-aligned t-block so the in-register P from swapped
// QK^T feeds PV's A-operand with zero cross-lane movement.
// phys = (e>>2)*16 + g*4 + (e&3) for storage k' = g*8 + e.
// ---------------------------------------------------------------------------
__global__ __launch_bounds__(256) void vtrans_kernel(
    const short* __restrict__ Vrm, short* __restrict__ Vt)
{
    const int t0 = blockIdx.x * 64;
    const int d0 = blockIdx.y * 64;
    const int hb = blockIdx.z;
    const int tid = threadIdx.x;
    __shared__ __align__(16) short tile[64 * 72];

#pragma unroll
    for (int k = 0; k < 2; ++k) {
        int q = tid + 256 * k;
        int row = q >> 3, slot = q & 7;
        s16x8 v = *(const s16x8*)(Vrm + ((size_t)hb * 2048 + t0 + row) * 1024 + d0 + slot * 8);
        *(s16x8*)&tile[row * 72 + slot * 8] = v;
    }
    __syncthreads();
#pragma unroll
    for (int k = 0; k < 2; ++k) {
        int q = tid + 256 * k;
        int drow = q >> 3, tslot = q & 7;
        s16x8 v;
#pragma unroll
        for (int i = 0; i < 8; ++i) {
            int c = tslot * 8 + i;
            int cl = c & 31;
            int src = (c & 32) + ((cl >> 2) & 1) * 16 + ((cl >> 4) & 1) * 8
                    + ((cl >> 3) & 1) * 4 + (cl & 3);
            v[i] = tile[src * 72 + drow];
        }
        *(s16x8*)(Vt + ((size_t)hb * 1024 + d0 + drow) * 2048 + t0 + tslot * 8) = v;
    }
}

// ---------------------------------------------------------------------------
// Kernel 3: flash attention — 32-q QK^T waves (K-read redundancy halved).
// Grid (8 hb, 16 qt, 2 dh) = 256 blocks, 512 thr (8 waves). QBLK=128,
// KBLK=32, 64 k-tiles.
// QK^T: wave (qs2 = wid>>1, kp = wid&1) owns 32 q-rows x 16-key half:
//   8 K-frag reads feed 16 MFMA (each ka reused across both 16-q subtiles).
//   Softmax in-register; each wave writes its kp half of pa as ds_write_b64
//   (same-lane correspondence; pi unchanged).
// PV: wave owns 64-d slice of the 512 half; 4 V reads + 8 P reads -> 32 MFMA.
// K quad-buffered (staged 3 ahead), V+P double-buffered; per-tile barrier =
// s_waitcnt vmcnt(2) (only the 2 K chunks float; V fully drained - fixes
// r15's miscounted vmcnt(4)).
// LDS: K 4x16K + V 2x32K + P 2x8K = 144 KB. Regs: qf 64 + oacc 128 AGPR.
// ---------------------------------------------------------------------------
__global__ __launch_bounds__(512, 2) void attn_kernel(
    const short* __restrict__ Qg, const short* __restrict__ Kg,
    const short* __restrict__ Vt, short* __restrict__ Ob)
{
    const int hb = blockIdx.x;
    const int qt = blockIdx.y;     // 0..15
    const int dh = blockIdx.z;     // 0..1
    const int t0 = qt * 128;
    const int tid = threadIdx.x;
    const int lane = tid & 63;
    const int wid = tid >> 6;
    const int qs2 = wid >> 1;      // 32-q group (QK^T)
    const int kp = wid & 1;        // 16-key half (QK^T)
    const int g = lane >> 4, c16 = lane & 15;

    __shared__ __align__(16) short k_lds[4][32 * 256];   // 4x16 KB
    __shared__ __align__(16) short v_lds[2][512 * 32];   // 2x32 KB
    __shared__ __align__(16) short p_lds[2][8][512];     // 2x8 KB
    __shared__ float l_sh[2][128];

    const size_t kgbase = (size_t)hb * 2048 * 256;
    const size_t vgbase = ((size_t)hb * 1024 + dh * 512) * 2048;
    const int dsl = wid * 64;      // this wave's d-slice within the 512 half

    // Q B-fragments for subtiles 2*qs2 (A) and 2*qs2+1 (B), persistent
    const size_t qrowA = (size_t)hb * 2048 + t0 + qs2 * 32 + c16;
    s16x8 qfA[8], qfB[8];
#pragma unroll
    for (int kf = 0; kf < 8; ++kf) {
        qfA[kf] = *(const s16x8*)(Qg + qrowA * 256 + kf * 32 + g * 8);
        qfB[kf] = *(const s16x8*)(Qg + (qrowA + 16) * 256 + kf * 32 + g * 8);
    }

    f32x4 oacc[32];                // [qs 0..7][dt 0..3]
#pragma unroll
    for (int i = 0; i < 32; ++i)
#pragma unroll
        for (int r = 0; r < 4; ++r) oacc[i][r] = 0.f;

    float l_rA = 0.f, l_rB = 0.f;  // partial softmax denoms (kp half)

#define STAGE_K(buf, kt) do {                                                  \
    _Pragma("unroll")                                                          \
    for (int j_ = 0; j_ < 2; ++j_) {                                           \
        int c_ = tid + 512 * j_;                                               \
        int row_ = c_ >> 5, sp_ = c_ & 31;                                     \
        int sl_ = sp_ ^ (row_ & 7);                                            \
        gload16(Kg + kgbase + (size_t)((kt) * 32 + row_) * 256 + sl_ * 8,      \
                &k_lds[buf][c_ * 8]);                                          \
    }                                                                          \
} while (0)

#define STAGE_V(buf, kt) do {                                                  \
    _Pragma("unroll")                                                          \
    for (int j_ = 0; j_ < 4; ++j_) {                                           \
        int c_ = tid + 512 * j_;                                               \
        int row_ = c_ >> 2, sp_ = c_ & 3;                                      \
        int sl_ = sp_ ^ ((row_ >> 1) & 3);                                     \
        gload16(Vt + vgbase + (size_t)row_ * 2048 + (kt) * 32 + sl_ * 8,       \
                &v_lds[buf][c_ * 8]);                                          \
    }                                                                          \
} while (0)

    // QK^T tile nt: 32 q x 16 keys (kp half). 8 ka reads -> 16 MFMA.
    // sfX[r] = S[phys key kp*16 + g*4 + r][q = c16 (+subtile)].
    // Each wave writes its kp half (4 bf16, b64) of the pa slots.
#define QKT_PHASE(nt) do {                                                     \
    f32x4 sfA, sfB;                                                            \
    _Pragma("unroll")                                                          \
    for (int r = 0; r < 4; ++r) { sfA[r] = 0.f; sfB[r] = 0.f; }                \
    __builtin_amdgcn_s_setprio(1);                                             \
    _Pragma("unroll")                                                          \
    for (int kf = 0; kf < 8; ++kf) {                                           \
        int sl_ = ((kf * 4 + g) ^ (c16 & 7)) * 8;                              \
        s16x8 ka = *(const s16x8*)&k_lds[(nt) & 3][(kp * 16 + c16) * 256 + sl_]; \
        sfA = __builtin_amdgcn_mfma_f32_16x16x32_bf16(ka, qfA[kf], sfA, 0, 0, 0); \
        sfB = __builtin_amdgcn_mfma_f32_16x16x32_bf16(ka, qfB[kf], sfB, 0, 0, 0); \
    }                                                                          \
    __builtin_amdgcn_s_setprio(0);                                             \
    float rsA = 0.f, rsB = 0.f;                                                \
    _Pragma("unroll")                                                          \
    for (int r = 0; r < 4; ++r) {                                              \
        float pA = __expf(sfA[r] * 0.0625f);                                   \
        float pB = __expf(sfB[r] * 0.0625f);                                   \
        sfA[r] = pA; sfB[r] = pB;                                              \
        rsA += pA; rsB += pB;                                                  \
    }                                                                          \
    rsA += __shfl_xor(rsA, 16); rsA += __shfl_xor(rsA, 32);                    \
    rsB += __shfl_xor(rsB, 16); rsB += __shfl_xor(rsB, 32);                    \
    l_rA += rsA; l_rB += rsB;                                                  \
    s16x4 pkA, pkB;                                                            \
    _Pragma("unroll")                                                          \
    for (int r = 0; r < 4; ++r) { pkA[r] = f2bf(sfA[r]); pkB[r] = f2bf(sfB[r]); } \
    *(s16x4*)&p_lds[(nt) & 1][qs2 * 2][lane * 8 + kp * 4] = pkA;               \
    *(s16x4*)&p_lds[(nt) & 1][qs2 * 2 + 1][lane * 8 + kp * 4] = pkB;           \
} while (0)

    // counted barrier: only the 2 newest VMEM ops (K DMA) float across
#define TILE_BARRIER2() do {                                                   \
    __builtin_amdgcn_sched_barrier(0);                                         \
    asm volatile("s_waitcnt vmcnt(2) lgkmcnt(0)" ::: "memory");                \
    __builtin_amdgcn_sched_barrier(0);                                         \
    __builtin_amdgcn_s_barrier();                                              \
} while (0)
#define TILE_BARRIER0() do {                                                   \
    __builtin_amdgcn_sched_barrier(0);                                         \
    asm volatile("s_waitcnt vmcnt(0) lgkmcnt(0)" ::: "memory");                \
    __builtin_amdgcn_sched_barrier(0);                                         \
    __builtin_amdgcn_s_barrier();                                              \
} while (0)

    // prologue: K0,K1,V0 staged and drained; K2 issued (floats), QKT(0)
    STAGE_K(0, 0);
    STAGE_K(1, 1);
    STAGE_V(0, 0);
    __syncthreads();               // full drain: K0,K1,V0 + qf ready
    STAGE_K(2, 2);                 // in flight across next barrier
    QKT_PHASE(0);                  // reads k[0], writes p[0]
    TILE_BARRIER2();               // p[0] visible, K2 floats

    for (int t = 0; t < 64; ++t) {
        const int buf = t & 1;

        if (t < 63) STAGE_V(buf ^ 1, t + 1);   // issued FIRST (must retire)
        if (t < 61) STAGE_K((t + 3) & 3, t + 3);  // issued LAST (floats)
        if (t < 63) QKT_PHASE(t + 1);          // k[(t+1)&3], writes p[buf^1]

        // PV(t): 4 V B-frags (reused across 8 q-subtiles) + 8 P A-frags
        s16x8 vb[4];
#pragma unroll
        for (int dt = 0; dt < 4; ++dt) {
            int rowv = dsl + dt * 16 + c16;
            vb[dt] = *(const s16x8*)&v_lds[buf][rowv * 32 + ((g ^ ((c16 >> 1) & 3)) * 8)];
        }
        __builtin_amdgcn_s_setprio(1);
#pragma unroll
        for (int qs = 0; qs < 8; ++qs) {
            s16x8 pa = *(const s16x8*)&p_lds[buf][qs][lane * 8];
#pragma unroll
            for (int dt = 0; dt < 4; ++dt)
                oacc[qs * 4 + dt] = __builtin_amdgcn_mfma_f32_16x16x32_bf16(
                    pa, vb[dt], oacc[qs * 4 + dt], 0, 0, 0);
        }
        __builtin_amdgcn_s_setprio(0);

        if (t < 61)      TILE_BARRIER2();
        else if (t < 63) TILE_BARRIER0();
    }

#undef STAGE_K
#undef STAGE_V
#undef QKT_PHASE
#undef TILE_BARRIER2
#undef TILE_BARRIER0

    // combine softmax denominators across the two kp halves
    __syncthreads();
    if (lane < 16) {
        l_sh[kp][qs2 * 32 + lane] = l_rA;
        l_sh[kp][qs2 * 32 + 16 + lane] = l_rB;
    }
    __syncthreads();

    // epilogue: O /= l, write bf16 in [b][h*16+ov][t][f] layout
    const int h = hb >> 1, b = hb & 1;
#pragma unroll
    for (int qs = 0; qs < 8; ++qs) {
        float li[4];
#pragma unroll
        for (int r = 0; r < 4; ++r) {
            int row = qs * 16 + g * 4 + r;
            li[r] = 1.f / (l_sh[0][row] + l_sh[1][row]);
        }
#pragma unroll
        for (int dt = 0; dt < 4; ++dt) {
            int vcol = dh * 512 + dsl + dt * 16 + c16;
            int cout = h * 16 + (vcol >> 6), ff = vcol & 63;
#pragma unroll
            for (int r = 0; r < 4; ++r) {
                int trow = t0 + qs * 16 + g * 4 + r;
                Ob[(((size_t)b * 64 + cout) * 2048 + trow) * 64 + ff] =
                    f2bf(oacc[qs * 4 + dt][r] * li[r]);
            }
        }
    }
}

// ---------------------------------------------------------------------------
// Kernel 4: output projection via MFMA + PReLU + LN(C,F) + residual
// (Wp bf16 conversion fused)
// ---------------------------------------------------------------------------
__global__ __launch_bounds__(256) void oproj_kernel(
    const short* __restrict__ Ob, const float* __restrict__ x,
    const float* __restrict__ Wp,
    const float* __restrict__ bp, const float* __restrict__ ap,
    const float* __restrict__ gp, const float* __restrict__ betp,
    float* __restrict__ out)
{
    const int t = blockIdx.x;
    const int b = blockIdx.y;
    const int tid = threadIdx.x;
    const int wid = tid >> 6, lane = tid & 63;
    const int g = lane >> 4, c16 = lane & 15;
    const int f_ = tid & 63, cg = tid >> 6;

    __shared__ __align__(16) short wp[64 * 64];
    __shared__ __align__(16) short os[64 * 64];
    __shared__ float zs[64 * 64];
    __shared__ float red[4][2];

#pragma unroll
    for (int j = 0; j < 2; ++j) {
        int i8 = tid + 256 * j;
        int row = i8 >> 3, cb = i8 & 7;
        f32x4 a0 = *(const f32x4*)(Wp + i8 * 8);
        f32x4 a1 = *(const f32x4*)(Wp + i8 * 8 + 4);
        s16x8 v;
#pragma unroll
        for (int i = 0; i < 4; ++i) { v[i] = f2bf(a0[i]); v[4 + i] = f2bf(a1[i]); }
        *(s16x8*)&wp[row * 64 + ((cb ^ (row & 7)) * 8)] = v;
    }
#pragma unroll
    for (int it = 0; it < 2; ++it) {
        int cb = cg + 4 * it, c0 = cb * 8;
        s16x8 v;
#pragma unroll
        for (int i = 0; i < 8; ++i)
            v[i] = Ob[(((size_t)b * 64 + c0 + i) * 2048 + t) * 64 + f_];
        *(s16x8*)&os[f_ * 64 + ((cb ^ (f_ & 7)) * 8)] = v;
    }
    __syncthreads();

    const int f0 = wid * 16;
    s16x8 bfr[2];
#pragma unroll
    for (int kk = 0; kk < 2; ++kk)
        bfr[kk] = *(const s16x8*)&os[(f0 + c16) * 64 + (((kk * 4 + g) ^ (c16 & 7)) * 8)];

    const float ap0 = ap[0];
    f32x4 acc[4];
#pragma unroll
    for (int rt = 0; rt < 4; ++rt) {
#pragma unroll
        for (int r = 0; r < 4; ++r) acc[rt][r] = 0.f;
#pragma unroll
        for (int kk = 0; kk < 2; ++kk) {
            s16x8 a = *(const s16x8*)&wp[(rt * 16 + c16) * 64 + (((kk * 4 + g) ^ (c16 & 7)) * 8)];
            acc[rt] = __builtin_amdgcn_mfma_f32_16x16x32_bf16(a, bfr[kk], acc[rt], 0, 0, 0);
        }
    }

#pragma unroll
    for (int rt = 0; rt < 4; ++rt)
#pragma unroll
        for (int r = 0; r < 4; ++r) {
            int row = rt * 16 + g * 4 + r;
            float z = acc[rt][r] + bp[row];
            z = z >= 0.f ? z : ap0 * z;
            zs[row * 64 + f0 + c16] = z;
        }
    __syncthreads();

    float s = 0.f, ss = 0.f;
#pragma unroll
    for (int j = 0; j < 16; ++j) {
        float v = zs[(cg + 4 * j) * 64 + f_];
        s += v; ss += v * v;
    }
#pragma unroll
    for (int msk = 32; msk >= 1; msk >>= 1) {
        s  += __shfl_xor(s, msk);
        ss += __shfl_xor(ss, msk);
    }
    if (lane == 0) { red[wid][0] = s; red[wid][1] = ss; }
    __syncthreads();
    float ts  = red[0][0] + red[1][0] + red[2][0] + red[3][0];
    float tss = red[0][1] + red[1][1] + red[2][1] + red[3][1];
    float mean = ts * (1.f / 4096.f);
    float rstd = rsqrtf(tss * (1.f / 4096.f) - mean * mean + EPS_);

#pragma unroll
    for (int j = 0; j < 16; ++j) {
        int row = cg + 4 * j;
        size_t idx = (((size_t)b * 64 + row) * 2048 + t) * 64 + f_;
        out[idx] = (zs[row * 64 + f_] - mean) * rstd * gp[row * 64 + f_]
                 + betp[row * 64 + f_] + x[idx];
    }
}

// ---------------------------------------------------------------------------
extern "C" void kernel_launch(void* const* d_in, const int* in_sizes, int n_in,
                              void* d_out, int out_size, void* d_ws, size_t ws_size,
                              hipStream_t stream)
{
    const float* x    = (const float*)d_in[0];
    const float* Wq   = (const float*)d_in[1];
    const float* bq   = (const float*)d_in[2];
    const float* aq   = (const float*)d_in[3];
    const float* gq   = (const float*)d_in[4];
    const float* betq = (const float*)d_in[5];
    const float* Wk   = (const float*)d_in[6];
    const float* bk   = (const float*)d_in[7];
    const float* ak   = (const float*)d_in[8];
    const float* gk   = (const float*)d_in[9];
    const float* betk = (const float*)d_in[10];
    const float* Wv   = (const float*)d_in[11];
    const float* bv   = (const float*)d_in[12];
    const float* av   = (const float*)d_in[13];
    const float* gv   = (const float*)d_in[14];
    const float* betv = (const float*)d_in[15];
    const float* Wp   = (const float*)d_in[16];
    const float* bp   = (const float*)d_in[17];
    const float* ap   = (const float*)d_in[18];
    const float* gp   = (const float*)d_in[19];
    const float* betp = (const float*)d_in[20];

    short* Qb   = (short*)d_ws;
    short* Kb   = Qb   + (size_t)8 * 2048 * 256;
    short* Vrm  = Kb   + (size_t)8 * 2048 * 256;
    short* Vt   = Vrm  + (size_t)8 * 2048 * 1024;
    short* Obuf = Vt   + (size_t)8 * 2048 * 1024;

    qkv_kernel<<<dim3(2048, 2), 256, 0, stream>>>(x, Wq, Wk, Wv,
        bq, aq, gq, betq, bk, ak, gk, betk, bv, av, gv, betv, Qb, Kb, Vrm);
    vtrans_kernel<<<dim3(32, 16, 8), 256, 0, stream>>>(Vrm, Vt);
    attn_kernel<<<dim3(8, 16, 2), 512, 0, stream>>>(Qb, Kb, Vt, Obuf);
    oproj_kernel<<<dim3(2048, 2), 256, 0, stream>>>(Obuf, x, Wp,
        bp, ap, gp, betp, (float*)d_out);
}